// Round 10
// baseline (1549.005 us; speedup 1.0000x reference)
//
#include <hip/hip_runtime.h>
#include <hip/hip_bf16.h>
#include <math.h>

typedef __hip_bfloat16 bf16;
typedef __attribute__((ext_vector_type(4))) float f32x4;
typedef __attribute__((ext_vector_type(16))) float f32x16;
typedef __attribute__((ext_vector_type(8))) short s16x8;
typedef __attribute__((ext_vector_type(4))) short s16x4;

#define DEVI __device__ __forceinline__

constexpr int ZD = 8, HD = 96, WD = 180;
constexpr int WZ = 2, WH = 6, WWn = 12;
constexpr int MZ = 4, MH = 16, MW = 15;
constexpr int WP = 144, WN = 960;
constexpr int DIM = 384, HEADS = 12, DH = 32;
constexpr int TOK = ZD * HD * WD;            // 138240
constexpr size_t TOKDIM = (size_t)TOK * DIM; // 53084160
constexpr int NC = 3, CM = TOK / NC;         // 46080 rows/chunk, mb=360 (div 8)

DEVI short f2b(float f) {
    bf16 h = __float2bfloat16(f);
    return *reinterpret_cast<short*>(&h);
}

DEVI int row_to_token(int r) {
    int wn = r / WP;
    int p  = r - wn * WP;
    int mz = wn / (MH * MW);
    int rem = wn - mz * (MH * MW);
    int mh = rem / MW;
    int mw = rem - mh * MW;
    int lz = p / (WH * WWn);
    int rp = p - lz * (WH * WWn);
    int lh = rp / WWn;
    int lw = rp - lh * WWn;
    int zp = mz * WZ + lz + 1;  if (zp >= ZD) zp -= ZD;
    int hp = mh * WH + lh + 3;  if (hp >= HD) hp -= HD;
    int wp = mw * WWn + lw + 6; if (wp >= WD) wp -= WD;
    return (zp * HD + hp) * WD + wp;
}

// ---------------- prep kernels ----------------

__global__ __launch_bounds__(256)
void k_fill(float* __restrict__ out, int n, float v) {
    int i = blockIdx.x * blockDim.x + threadIdx.x;
    if (i < n) out[i] = v;
}

__global__ __launch_bounds__(256)
void k_wcast(const float* __restrict__ w, bf16* __restrict__ wt, int K, int N) {
    int idx = blockIdx.x * blockDim.x + threadIdx.x;
    if (idx >= K * N) return;
    int n = idx / K;
    int k = idx - n * K;
    wt[idx] = __float2bfloat16(w[(size_t)k * N + n]);
}

// btr[(wt*12+h)*3312 + pos] = bt[pos*768 + wt*12 + h] * log2(e)
__global__ __launch_bounds__(256)
void k_btr(const float* __restrict__ bt, float* __restrict__ btr) {
    int idx = blockIdx.x * blockDim.x + threadIdx.x;
    if (idx >= 64 * 12 * 3312) return;
    int wth = idx / 3312;
    int pos = idx - wth * 3312;
    btr[idx] = bt[(size_t)pos * 768 + wth] * 1.4426950408889634f;
}

// expand bias + (z,h)-region mask -> tab[(wt*12+h)][i][j], bf16, log2-scaled
__global__ __launch_bounds__(256)
void k_mktab(const float* __restrict__ btr, bf16* __restrict__ tab) {
    int idx = blockIdx.x * blockDim.x + threadIdx.x;
    if (idx >= 768 * WP * WP) return;
    int t = idx / (WP * WP);
    int e = idx - t * (WP * WP);
    int i = e / WP, j = e - i * WP;
    int wt = t / 12;
    int mz = wt >> 4, mh = wt & 15;
    int lzi = i / 72, ri_ = i - lzi * 72, lhi = ri_ / 12, lwi = ri_ - lhi * 12;
    int lzj = j / 72, rj_ = j - lzj * 72, lhj = rj_ / 12, lwj = rj_ - lhj * 12;
    int cA = lzi * 828 + lhi * 23 + lwi;
    int cB = lzj * 1656 + lhj * 138 + (11 - lwj);
    float vv = btr[(size_t)t * 3312 + cA + cB];
    int zri = (mz == 3) ? (lzi + 1) : 0, zrj = (mz == 3) ? (lzj + 1) : 0;
    int hri = (mh == 15) ? (lhi < 3 ? 1 : 2) : 0, hrj = (mh == 15) ? (lhj < 3 ? 1 : 2) : 0;
    if (zri != zrj || hri != hrj) vv -= 144.26950408889634f; // -100*log2(e)
    tab[idx] = __float2bfloat16(vv);
}

__global__ __launch_bounds__(256)
void k_gather_x(const float* __restrict__ x, bf16* __restrict__ xw) {
    int idx = blockIdx.x * blockDim.x + threadIdx.x;
    if (idx >= TOK * 96) return;
    int r  = idx / 96;
    int c4 = (idx - r * 96) * 4;
    int t  = row_to_token(r);
    const float4 vv = *(const float4*)(x + (size_t)t * DIM + c4);
    s16x4 o;
    o[0] = f2b(vv.x); o[1] = f2b(vv.y); o[2] = f2b(vv.z); o[3] = f2b(vv.w);
    *(s16x4*)((short*)xw + (size_t)r * DIM + c4) = o;
}

// ---------------- GEMM ----------------

DEVI void gload16(const bf16* g, bf16* l) {
    __builtin_amdgcn_global_load_lds(
        (const __attribute__((address_space(1))) void*)g,
        (__attribute__((address_space(3))) void*)l, 16, 0, 0);
}

// C = A(MxK) @ BT(NxK)^T via 32x32x16 MFMA, swapped operands (D = C^T in regs),
// BK=32 DOUBLE-BUFFERED 2-phase pipeline: issue next-tile global_load_lds BEFORE
// computing current tile, drain (vmcnt 0) only at iter end -> loads overlap MFMA.
// LDS 32KB total (same occupancy as single-buffer BK=64). T2 swizzle over 4 slots.
// XCD-grouped block swizzle (requires (M/128)%8==0).
// EPI 0: qkv scatter (q scaled by 1/sqrt(32)*log2e); EPI 1: +bias; EPI 2: +bias,GELU
template <int EPI>
__global__ __launch_bounds__(256)
void k_gemm(const bf16* __restrict__ A, const bf16* __restrict__ BT,
            const float* __restrict__ bias, bf16* __restrict__ out,
            int M, int N, int K) {
    constexpr int BK = 32;
    __shared__ bf16 As[2][128 * BK];
    __shared__ bf16 Bs[2][128 * BK];

    const int nb = N >> 7;
    const int g = blockIdx.x;
    const int xcd = g & 7;
    const int ii = g >> 3;
    const int tt = ii / nb;
    const int bm = tt * 8 + xcd;
    const int bn = ii - tt * nb;

    const int tid = threadIdx.x;
    const int lane = tid & 63;
    const int wv = tid >> 6;
    const int wr = wv >> 1;          // feature-half (N-dim)
    const int wc = wv & 1;           // token-half (M-dim)
    const int l31 = lane & 31, hi = lane >> 5;

    const bf16* Ab = A + (size_t)bm * 128 * K;
    const bf16* Bb = BT + (size_t)bn * 128 * K;

    // staging: per wave-issue, HW writes lane*16B at uniform LDS base.
    // lane covers row (16wv + lane>>2 + 64i), slot (lane&3); source col swizzled.
    const int srow = lane >> 2;
    const int sslot = lane & 3;

    f32x16 acc[2][2] = {{{}, {}}, {{}, {}}};

    int ra[2], rb[2], rax[2], rbx[2];
#pragma unroll
    for (int i2 = 0; i2 < 2; i2++) {
        ra[i2] = 64 * wr + 32 * i2 + l31; rax[i2] = ra[i2] & 3;
        rb[i2] = 64 * wc + 32 * i2 + l31; rbx[i2] = rb[i2] & 3;
    }

    const int kiters = K / BK;

    auto stage = [&](int buf, int k0) {
#pragma unroll
        for (int i = 0; i < 2; i++) {
            int r = i * 64 + wv * 16 + srow;
            int sl = (sslot ^ (r & 3)) * 8;
            gload16(Ab + (size_t)r * K + k0 + sl, &As[buf][i * 2048 + wv * 512]);
            gload16(Bb + (size_t)r * K + k0 + sl, &Bs[buf][i * 2048 + wv * 512]);
        }
    };

    stage(0, 0);
    asm volatile("s_waitcnt vmcnt(0)" ::: "memory");
    __syncthreads();

    int cur = 0;
    for (int kt = 0; kt < kiters; kt++) {
        if (kt + 1 < kiters) stage(cur ^ 1, (kt + 1) * BK);   // prefetch in flight
#pragma unroll
        for (int kk = 0; kk < 2; kk++) {
            const int s0 = 2 * kk + hi;                       // 16B-slot 0..3
            s16x8 af[2], bfv[2];
#pragma unroll
            for (int ni = 0; ni < 2; ni++)
                af[ni] = *(const s16x8*)&Bs[cur][ra[ni] * BK + ((s0 ^ rax[ni]) * 8)];
#pragma unroll
            for (int mi = 0; mi < 2; mi++)
                bfv[mi] = *(const s16x8*)&As[cur][rb[mi] * BK + ((s0 ^ rbx[mi]) * 8)];
#pragma unroll
            for (int ni = 0; ni < 2; ni++)
#pragma unroll
                for (int mi = 0; mi < 2; mi++)
                    acc[ni][mi] = __builtin_amdgcn_mfma_f32_32x32x16_bf16(
                        af[ni], bfv[mi], acc[ni][mi], 0, 0, 0);
        }
        // drain prefetch writes before barrier (replay-race-safe discipline)
        asm volatile("s_waitcnt vmcnt(0)" ::: "memory");
        __syncthreads();
        cur ^= 1;
    }

    // epilogue: D[row=feature][col=token]; reg 4*rq+r2 -> feature (8*rq+4*hi+r2)
    const int tokbase = bm * 128 + 64 * wc + l31;
    const int featbase = bn * 128 + 64 * wr + 4 * hi;
#pragma unroll
    for (int ni = 0; ni < 2; ni++) {
#pragma unroll
        for (int mi = 0; mi < 2; mi++) {
            const int tok = tokbase + 32 * mi;
#pragma unroll
            for (int rq = 0; rq < 4; rq++) {
                const int f0 = featbase + 32 * ni + 8 * rq;
                float v0 = acc[ni][mi][4 * rq + 0];
                float v1 = acc[ni][mi][4 * rq + 1];
                float v2 = acc[ni][mi][4 * rq + 2];
                float v3 = acc[ni][mi][4 * rq + 3];
                if constexpr (EPI == 0) {
                    const int which = f0 / DIM;
                    const int rem = f0 - which * DIM;
                    const int head = rem >> 5, dh = rem & 31;
                    if (which == 0) {
                        v0 *= 0.25503527f; v1 *= 0.25503527f; // (1/sqrt(32))*log2(e)
                        v2 *= 0.25503527f; v3 *= 0.25503527f;
                    }
                    const int wn = tok / WP, p = tok - wn * WP;
                    s16x4 o; o[0] = f2b(v0); o[1] = f2b(v1); o[2] = f2b(v2); o[3] = f2b(v3);
                    *(s16x4*)(out + (size_t)which * TOKDIM +
                              ((size_t)(wn * HEADS + head) * WP + p) * DH + dh) = o;
                } else if constexpr (EPI == 1) {
                    const float4 bv = *(const float4*)(bias + f0);
                    s16x4 o;
                    o[0] = f2b(v0 + bv.x); o[1] = f2b(v1 + bv.y);
                    o[2] = f2b(v2 + bv.z); o[3] = f2b(v3 + bv.w);
                    *(s16x4*)(out + (size_t)tok * N + f0) = o;
                } else {
                    const float4 bv = *(const float4*)(bias + f0);
                    float g0 = v0 + bv.x, g1 = v1 + bv.y, g2 = v2 + bv.z, g3 = v3 + bv.w;
                    g0 = 0.5f * g0 * (1.0f + erff(g0 * 0.70710678118654752f));
                    g1 = 0.5f * g1 * (1.0f + erff(g1 * 0.70710678118654752f));
                    g2 = 0.5f * g2 * (1.0f + erff(g2 * 0.70710678118654752f));
                    g3 = 0.5f * g3 * (1.0f + erff(g3 * 0.70710678118654752f));
                    s16x4 o; o[0] = f2b(g0); o[1] = f2b(g1); o[2] = f2b(g2); o[3] = f2b(g3);
                    *(s16x4*)(out + (size_t)tok * N + f0) = o;
                }
            }
        }
    }
}

// ---------------- fused window attention ----------------
// block = one (window, head); 3 waves; wave s owns strips {3s,3s+1,3s+2}.
// Q and K fragments direct from global (coalesced, L1/L2-hit); only V^T + P in LDS
// (26.4KB -> 6 blocks/CU for latency hiding). Strides 164 (conflict-free walk).
// Softmax in exp2 domain, no max-subtract, normalize O after PV.
__global__ __launch_bounds__(192)
void k_attn(const bf16* __restrict__ q, const bf16* __restrict__ kmat,
            const bf16* __restrict__ v, const bf16* __restrict__ tab,
            bf16* __restrict__ out) {
    __shared__ bf16 VTs[DH * 164];      // [32][164], cols 144..163 zero
    __shared__ bf16 Ps[3][16 * 164];    // per-wave [16][164], cols 144..159 zero
    __shared__ unsigned char regn[WP];

    const int bid = blockIdx.x;
    const int wn = bid / HEADS, head = bid - wn * HEADS;
    const int mz = wn / (MH * MW);
    const int rem = wn - mz * (MH * MW);
    const int mh = rem / MW, mw = rem - (rem / MW) * MW;
    const int tile = (mz * MH + mh) * HEADS + head;   // wt*12 + head

    const int tid = threadIdx.x;
    const int lane = tid & 63;
    const int s = tid >> 6;              // wave 0..2
    const int lg = lane >> 4, lc = lane & 15;

    const size_t base = (size_t)(wn * HEADS + head) * (WP * DH);
    // stage V transposed [32][164]
    {
        short* vt = (short*)VTs;
#pragma unroll
        for (int e2 = 0; e2 < 3; e2++) {
            int idx = tid + 192 * e2;    // 0..575
            s16x8 vv = *(const s16x8*)(v + base + idx * 8);
            int p = idx >> 2;
            int d0 = (idx & 3) * 8;
#pragma unroll
            for (int e = 0; e < 8; e++) vt[(d0 + e) * 164 + p] = vv[e];
        }
        // zero VT cols 144..163 (32 rows x 20 cols, 160 s16x4 stores)
        if (tid < 160) {
            int d = tid / 5, gq = tid - d * 5;
            *(s16x4*)(vt + d * 164 + 144 + gq * 4) = (s16x4){0, 0, 0, 0};
        }
        // zero this wave's Ps pad cols 144..159 (16 rows x 16 cols)
        { short* pz = (short*)&Ps[s][0];
          *(s16x4*)(pz + (lane >> 2) * 164 + 144 + (lane & 3) * 4) = (s16x4){0, 0, 0, 0}; }
        if (tid < WP) {
            int lz = tid / 72, rp = tid - lz * 72;
            int lh = rp / 12, lw = rp - lh * 12;
            int zr = (mz == 3) ? (lz + 1) : 0;
            int hr = (mh == 15) ? (lh < 3 ? 1 : 2) : 0;
            int wbit = (lw < 6) ? 1 : 2;
            regn[tid] = (unsigned char)((zr * 3 + hr) * 4 + wbit);
        }
    }
    __syncthreads();

    const f32x4 zf = {0.f, 0.f, 0.f, 0.f};
    const bf16* tb = tab + (size_t)tile * (WP * WP);
    const bf16* kb = kmat + base;
    bf16* ob = out + (size_t)wn * (WP * DIM) + head * DH;
    short* ps = (short*)&Ps[s][0];
    const bf16* psb = &Ps[s][0];

    for (int t = 0; t < 3; t++) {
        const int strip = 3 * s + t;
        const int ib = 16 * strip + 4 * lg;
        // Q fragment direct from global
        s16x8 aq = *(const s16x8*)(q + base + (size_t)(16 * strip + lc) * DH + 8 * lg);
        f32x4 sacc[9];
        // QK^T; K fragments direct from global (1KB coalesced per jt, L1/L2-hit)
#pragma unroll
        for (int jt = 0; jt < 9; jt++) {
            s16x8 bk = *(const s16x8*)(kb + (size_t)(16 * jt + lc) * DH + 8 * lg);
            sacc[jt] = __builtin_amdgcn_mfma_f32_16x16x32_bf16(aq, bk, zf, 0, 0, 0);
        }
        // + expanded bias (includes z/h mask), log2-scaled
#pragma unroll
        for (int jt = 0; jt < 9; jt++) {
            int j = 16 * jt + lc;
#pragma unroll
            for (int r2 = 0; r2 < 4; r2++)
                sacc[jt][r2] += __bfloat162float(tb[(ib + r2) * WP + j]);
        }
        // residual w-region mask (only boundary-mw windows)
        if (mw == 14) {
            int ri[4];
#pragma unroll
            for (int r2 = 0; r2 < 4; r2++) ri[r2] = regn[ib + r2];
#pragma unroll
            for (int jt = 0; jt < 9; jt++) {
                int rj = regn[16 * jt + lc];
#pragma unroll
                for (int r2 = 0; r2 < 4; r2++) {
                    bool m = ((ri[r2] >> 2) == (rj >> 2)) && ((ri[r2] & 3) != (rj & 3));
                    if (m) sacc[jt][r2] -= 144.2695f;
                }
            }
        }
        // exp2 (no max-subtract) + row sums
        float inv[4];
#pragma unroll
        for (int r2 = 0; r2 < 4; r2++) {
            float sum = 0.f;
#pragma unroll
            for (int jt = 0; jt < 9; jt++) {
                float pe = exp2f(sacc[jt][r2]);
                sacc[jt][r2] = pe;
                sum += pe;
            }
#pragma unroll
            for (int o = 1; o < 16; o <<= 1) sum += __shfl_xor(sum, o);
            inv[r2] = 1.0f / sum;
        }
        // store unnormalized P row-major [16][164] (wave-private; no barrier needed)
#pragma unroll
        for (int jt = 0; jt < 9; jt++)
#pragma unroll
            for (int r2 = 0; r2 < 4; r2++)
                ps[(4 * lg + r2) * 164 + 16 * jt + lc] = f2b(sacc[jt][r2]);
        // PV : O[16 x 32] (b128 fragment reads; compiler inserts lgkmcnt for RAW)
        f32x4 oacc[2] = {zf, zf};
#pragma unroll
        for (int c = 0; c < 5; c++) {
            s16x8 ap = *(const s16x8*)(psb + lc * 164 + 32 * c + 8 * lg);
#pragma unroll
            for (int nt = 0; nt < 2; nt++) {
                s16x8 bv = *(const s16x8*)(VTs + (16 * nt + lc) * 164 + 32 * c + 8 * lg);
                oacc[nt] = __builtin_amdgcn_mfma_f32_16x16x32_bf16(ap, bv, oacc[nt], 0, 0, 0);
            }
        }
#pragma unroll
        for (int nt = 0; nt < 2; nt++)
#pragma unroll
            for (int r2 = 0; r2 < 4; r2++)
                ob[(size_t)(ib + r2) * DIM + 16 * nt + lc] =
                    __float2bfloat16(oacc[nt][r2] * inv[r2]);
    }
}

// ---------------- LayerNorm kernels (wave-per-row, no LDS/barrier) ----------------

__global__ __launch_bounds__(256)
void k_ln1(const bf16* __restrict__ y, const float* __restrict__ x,
           const float* __restrict__ w, const float* __restrict__ b,
           bf16* __restrict__ x1b, int r0) {
    const int row = blockIdx.x * 4 + (threadIdx.x >> 6);
    const int l = threadIdx.x & 63;
    const int t = row_to_token(r0 + row);
    const short* yr = (const short*)y + (size_t)row * DIM;
    float v[6];
#pragma unroll
    for (int e = 0; e < 3; e++) {
        int c = 128 * e + 2 * l;
        unsigned int u = *(const unsigned int*)(yr + c);
        unsigned int lo = (u & 0xffffu) << 16, hiu = u & 0xffff0000u;
        v[2 * e]     = *reinterpret_cast<float*>(&lo);
        v[2 * e + 1] = *reinterpret_cast<float*>(&hiu);
    }
    float sum = 0.f, s2 = 0.f;
#pragma unroll
    for (int e = 0; e < 6; e++) { sum += v[e]; s2 += v[e] * v[e]; }
#pragma unroll
    for (int o = 1; o < 64; o <<= 1) { sum += __shfl_xor(sum, o); s2 += __shfl_xor(s2, o); }
    float mean = sum * (1.f / 384.f);
    float var = fmaxf(s2 * (1.f / 384.f) - mean * mean, 0.f);
    float rs = rsqrtf(var + 1e-5f);
#pragma unroll
    for (int e = 0; e < 3; e++) {
        int c = 128 * e + 2 * l;
        const float2 wv2 = *(const float2*)(w + c);
        const float2 bv2 = *(const float2*)(b + c);
        const float2 xx = *(const float2*)(x + (size_t)t * DIM + c);
        float o0 = (v[2 * e] - mean) * rs * wv2.x + bv2.x + xx.x;
        float o1 = (v[2 * e + 1] - mean) * rs * wv2.y + bv2.y + xx.y;
        short2 st; st.x = f2b(o0); st.y = f2b(o1);
        *(short2*)((short*)x1b + (size_t)t * DIM + c) = st;
    }
}

__global__ __launch_bounds__(256)
void k_ln2(const bf16* __restrict__ h, const bf16* __restrict__ x1b,
           const float* __restrict__ w, const float* __restrict__ b,
           float* __restrict__ out) {
    const int row = blockIdx.x * 4 + (threadIdx.x >> 6);
    const int l = threadIdx.x & 63;
    const short* hr = (const short*)h + (size_t)row * DIM;
    float v[6];
#pragma unroll
    for (int e = 0; e < 3; e++) {
        int c = 128 * e + 2 * l;
        unsigned int u = *(const unsigned int*)(hr + c);
        unsigned int lo = (u & 0xffffu) << 16, hiu = u & 0xffff0000u;
        v[2 * e]     = *reinterpret_cast<float*>(&lo);
        v[2 * e + 1] = *reinterpret_cast<float*>(&hiu);
    }
    float sum = 0.f, s2 = 0.f;
#pragma unroll
    for (int e = 0; e < 6; e++) { sum += v[e]; s2 += v[e] * v[e]; }
#pragma unroll
    for (int o = 1; o < 64; o <<= 1) { sum += __shfl_xor(sum, o); s2 += __shfl_xor(s2, o); }
    float mean = sum * (1.f / 384.f);
    float var = fmaxf(s2 * (1.f / 384.f) - mean * mean, 0.f);
    float rs = rsqrtf(var + 1e-5f);
    const short* xr = (const short*)x1b + (size_t)row * DIM;
#pragma unroll
    for (int e = 0; e < 3; e++) {
        int c = 128 * e + 2 * l;
        const float2 wv2 = *(const float2*)(w + c);
        const float2 bv2 = *(const float2*)(b + c);
        unsigned int u = *(const unsigned int*)(xr + c);
        unsigned int lo = (u & 0xffffu) << 16, hiu = u & 0xffff0000u;
        float2 o2;
        o2.x = (v[2 * e] - mean) * rs * wv2.x + bv2.x + *reinterpret_cast<float*>(&lo);
        o2.y = (v[2 * e + 1] - mean) * rs * wv2.y + bv2.y + *reinterpret_cast<float*>(&hiu);
        *(float2*)(out + (size_t)row * DIM + c) = o2;
    }
}

// ---------------- launcher ----------------
// Workspace map (bytes):
//  0         wqkvT(884736) wprojT(294912) w1T(1179648) w2T(1179648)
//  3538944   btr f32 (10174464)
//  13713408  tab bf16 (31850496)
//  45563904  D1: qkv (318504960) -> x1b(106168320) + ytmp/h1c(141557760 @D1+106168320)
//  364068864 D2: xw -> aout -> htmp (106168320)
//  peak 470237184

extern "C" void kernel_launch(void* const* d_in, const int* in_sizes, int n_in,
                              void* d_out, int out_size, void* d_ws, size_t ws_size,
                              hipStream_t stream) {
    const float* x      = (const float*)d_in[0];
    const float* w_qkv  = (const float*)d_in[1];
    const float* w_proj = (const float*)d_in[2];
    const float* b_proj = (const float*)d_in[3];
    const float* btab   = (const float*)d_in[4];
    const float* ln1w   = (const float*)d_in[5];
    const float* ln1b   = (const float*)d_in[6];
    const float* ln2w   = (const float*)d_in[7];
    const float* ln2b   = (const float*)d_in[8];
    const float* w1     = (const float*)d_in[9];
    const float* b1     = (const float*)d_in[10];
    const float* w2     = (const float*)d_in[11];
    const float* b2     = (const float*)d_in[12];

    const size_t NEED = 470237184ULL;
    if (ws_size < NEED) {
        k_fill<<<(out_size + 255) / 256, 256, 0, stream>>>((float*)d_out, out_size, 12345.0f);
        return;
    }

    char* ws = (char*)d_ws;
    bf16* wqkvT  = (bf16*)(ws + 0);
    bf16* wprojT = (bf16*)(ws + 884736);
    bf16* w1T    = (bf16*)(ws + 1179648);
    bf16* w2T    = (bf16*)(ws + 2359296);
    float* btr   = (float*)(ws + 3538944);
    bf16* tab    = (bf16*)(ws + 13713408);

    const size_t D1 = 45563904;
    const size_t D2 = 364068864;

    bf16* qkv  = (bf16*)(ws + D1);
    bf16* x1b  = (bf16*)(ws + D1);
    bf16* ytmp = (bf16*)(ws + D1 + 106168320);
    bf16* h1c  = (bf16*)(ws + D1 + 106168320);
    bf16* xw   = (bf16*)(ws + D2);
    bf16* aout = (bf16*)(ws + D2);
    bf16* htmp = (bf16*)(ws + D2);

    // prep
    k_wcast<<<(442368 + 255) / 256, 256, 0, stream>>>(w_qkv, wqkvT, 384, 1152);
    k_wcast<<<(147456 + 255) / 256, 256, 0, stream>>>(w_proj, wprojT, 384, 384);
    k_wcast<<<(589824 + 255) / 256, 256, 0, stream>>>(w1, w1T, 384, 1536);
    k_wcast<<<(589824 + 255) / 256, 256, 0, stream>>>(w2, w2T, 1536, 384);
    k_btr<<<(2543616 + 255) / 256, 256, 0, stream>>>(btab, btr);
    k_mktab<<<(768 * WP * WP + 255) / 256, 256, 0, stream>>>(btr, tab);
    k_gather_x<<<(TOK * 96 + 255) / 256, 256, 0, stream>>>(x, xw);

    // qkv = xw @ w_qkv (scatter epilogue)
    k_gemm<0><<<dim3((TOK / 128) * 9), 256, 0, stream>>>(xw, wqkvT, nullptr, qkv, TOK, 1152, 384);

    // attention (192 threads, 3 waves, 6 blocks/CU)
    k_attn<<<dim3(WN * HEADS), 192, 0, stream>>>(qkv, qkv + TOKDIM, qkv + 2 * TOKDIM, tab, aout);

    // proj + LN1 + residual (chunked; qkv region becomes x1b)
    for (int c = 0; c < NC; c++) {
        k_gemm<1><<<dim3((CM / 128) * 3), 256, 0, stream>>>(
            aout + (size_t)c * CM * DIM, wprojT, b_proj, ytmp, CM, 384, 384);
        k_ln1<<<dim3(CM / 4), 256, 0, stream>>>(ytmp, x, ln1w, ln1b, x1b, c * CM);
    }

    // MLP (chunked)
    for (int c = 0; c < NC; c++) {
        k_gemm<2><<<dim3((CM / 128) * 12), 256, 0, stream>>>(
            x1b + (size_t)c * CM * DIM, w1T, b1, h1c, CM, 1536, 384);
        k_gemm<1><<<dim3((CM / 128) * 3), 256, 0, stream>>>(
            h1c, w2T, b2, htmp + (size_t)c * CM * DIM, CM, 384, 1536);
    }

    // final LN + residual -> d_out (fp32)
    k_ln2<<<dim3(TOK / 4), 256, 0, stream>>>(htmp, x1b, ln2w, ln2b, (float*)d_out);
}

// Round 11
// 1420.113 us; speedup vs baseline: 1.0908x; 1.0908x over previous
//
#include <hip/hip_runtime.h>
#include <hip/hip_bf16.h>
#include <math.h>

typedef __hip_bfloat16 bf16;
typedef __attribute__((ext_vector_type(4))) float f32x4;
typedef __attribute__((ext_vector_type(16))) float f32x16;
typedef __attribute__((ext_vector_type(8))) short s16x8;
typedef __attribute__((ext_vector_type(4))) short s16x4;

#define DEVI __device__ __forceinline__

constexpr int ZD = 8, HD = 96, WD = 180;
constexpr int WZ = 2, WH = 6, WWn = 12;
constexpr int MZ = 4, MH = 16, MW = 15;
constexpr int WP = 144, WN = 960;
constexpr int DIM = 384, HEADS = 12, DH = 32;
constexpr int TOK = ZD * HD * WD;            // 138240
constexpr size_t TOKDIM = (size_t)TOK * DIM; // 53084160
constexpr int NC = 3, CM = TOK / NC;         // 46080 rows/chunk, mb=360 (div 8)

DEVI short f2b(float f) {
    bf16 h = __float2bfloat16(f);
    return *reinterpret_cast<short*>(&h);
}

DEVI int row_to_token(int r) {
    int wn = r / WP;
    int p  = r - wn * WP;
    int mz = wn / (MH * MW);
    int rem = wn - mz * (MH * MW);
    int mh = rem / MW;
    int mw = rem - mh * MW;
    int lz = p / (WH * WWn);
    int rp = p - lz * (WH * WWn);
    int lh = rp / WWn;
    int lw = rp - lh * WWn;
    int zp = mz * WZ + lz + 1;  if (zp >= ZD) zp -= ZD;
    int hp = mh * WH + lh + 3;  if (hp >= HD) hp -= HD;
    int wp = mw * WWn + lw + 6; if (wp >= WD) wp -= WD;
    return (zp * HD + hp) * WD + wp;
}

// ---------------- prep kernels ----------------

__global__ __launch_bounds__(256)
void k_fill(float* __restrict__ out, int n, float v) {
    int i = blockIdx.x * blockDim.x + threadIdx.x;
    if (i < n) out[i] = v;
}

__global__ __launch_bounds__(256)
void k_wcast(const float* __restrict__ w, bf16* __restrict__ wt, int K, int N) {
    int idx = blockIdx.x * blockDim.x + threadIdx.x;
    if (idx >= K * N) return;
    int n = idx / K;
    int k = idx - n * K;
    wt[idx] = __float2bfloat16(w[(size_t)k * N + n]);
}

// btr[(wt*12+h)*3312 + pos] = bt[pos*768 + wt*12 + h] * log2(e)
__global__ __launch_bounds__(256)
void k_btr(const float* __restrict__ bt, float* __restrict__ btr) {
    int idx = blockIdx.x * blockDim.x + threadIdx.x;
    if (idx >= 64 * 12 * 3312) return;
    int wth = idx / 3312;
    int pos = idx - wth * 3312;
    btr[idx] = bt[(size_t)pos * 768 + wth] * 1.4426950408889634f;
}

// expand bias + (z,h)-region mask -> tab[(wt*12+h)][i][j], bf16, log2-scaled
__global__ __launch_bounds__(256)
void k_mktab(const float* __restrict__ btr, bf16* __restrict__ tab) {
    int idx = blockIdx.x * blockDim.x + threadIdx.x;
    if (idx >= 768 * WP * WP) return;
    int t = idx / (WP * WP);
    int e = idx - t * (WP * WP);
    int i = e / WP, j = e - i * WP;
    int wt = t / 12;
    int mz = wt >> 4, mh = wt & 15;
    int lzi = i / 72, ri_ = i - lzi * 72, lhi = ri_ / 12, lwi = ri_ - lhi * 12;
    int lzj = j / 72, rj_ = j - lzj * 72, lhj = rj_ / 12, lwj = rj_ - lhj * 12;
    int cA = lzi * 828 + lhi * 23 + lwi;
    int cB = lzj * 1656 + lhj * 138 + (11 - lwj);
    float vv = btr[(size_t)t * 3312 + cA + cB];
    int zri = (mz == 3) ? (lzi + 1) : 0, zrj = (mz == 3) ? (lzj + 1) : 0;
    int hri = (mh == 15) ? (lhi < 3 ? 1 : 2) : 0, hrj = (mh == 15) ? (lhj < 3 ? 1 : 2) : 0;
    if (zri != zrj || hri != hrj) vv -= 144.26950408889634f; // -100*log2(e)
    tab[idx] = __float2bfloat16(vv);
}

__global__ __launch_bounds__(256)
void k_gather_x(const float* __restrict__ x, bf16* __restrict__ xw) {
    int idx = blockIdx.x * blockDim.x + threadIdx.x;
    if (idx >= TOK * 96) return;
    int r  = idx / 96;
    int c4 = (idx - r * 96) * 4;
    int t  = row_to_token(r);
    const float4 vv = *(const float4*)(x + (size_t)t * DIM + c4);
    s16x4 o;
    o[0] = f2b(vv.x); o[1] = f2b(vv.y); o[2] = f2b(vv.z); o[3] = f2b(vv.w);
    *(s16x4*)((short*)xw + (size_t)r * DIM + c4) = o;
}

// ---------------- GEMM (round-9 proven: BK=64 single-buffer, 8-slot T2 swizzle) ----

DEVI void gload16(const bf16* g, bf16* l) {
    __builtin_amdgcn_global_load_lds(
        (const __attribute__((address_space(1))) void*)g,
        (__attribute__((address_space(3))) void*)l, 16, 0, 0);
}

// C = A(MxK) @ BT(NxK)^T via 32x32x16 MFMA with SWAPPED operands (weights = A-op,
// activations = B-op) so D = C^T in registers -> s16x4 stores. LDS tiles
// XOR-swizzled over 8 slots (pre-swizzled global source, linear LDS dest).
// XCD-grouped block swizzle (requires (M/128)%8==0).
// EPI 0: qkv scatter (q scaled by 1/sqrt(32)*log2e); EPI 1: +bias; EPI 2: +bias,GELU
template <int EPI>
__global__ __launch_bounds__(256)
void k_gemm(const bf16* __restrict__ A, const bf16* __restrict__ BT,
            const float* __restrict__ bias, bf16* __restrict__ out,
            int M, int N, int K) {
    constexpr int BK = 64;
    __shared__ bf16 As[128 * BK];
    __shared__ bf16 Bs[128 * BK];

    const int nb = N >> 7;
    const int g = blockIdx.x;
    const int xcd = g & 7;
    const int ii = g >> 3;
    const int tt = ii / nb;
    const int bm = tt * 8 + xcd;
    const int bn = ii - tt * nb;

    const int tid = threadIdx.x;
    const int lane = tid & 63;
    const int wv = tid >> 6;
    const int wr = wv >> 1;          // feature-half of wave tile (N-dim)
    const int wc = wv & 1;           // token-half (M-dim)
    const int l31 = lane & 31, hi = lane >> 5;

    const bf16* Ab = A + (size_t)bm * 128 * K;
    const bf16* Bb = BT + (size_t)bn * 128 * K;

    f32x16 acc[2][2] = {{{}, {}}, {{}, {}}};

    const int kiters = K / BK;
    const int srow = lane >> 3;                         // 0..7 within 8-row chunk
    const int scol = ((lane & 7) ^ srow) * 8;           // pre-swizzled k-offset (bf16)

    int ra[2], rb[2], rax[2], rbx[2];
#pragma unroll
    for (int i2 = 0; i2 < 2; i2++) {
        ra[i2] = 64 * wr + 32 * i2 + l31; rax[i2] = ra[i2] & 7;
        rb[i2] = 64 * wc + 32 * i2 + l31; rbx[i2] = rb[i2] & 7;
    }

    for (int kt = 0; kt < kiters; kt++) {
        const int k0 = kt * BK;
#pragma unroll
        for (int i = 0; i < 4; i++) {
            int ch = wv * 4 + i;
            int row = ch * 8 + srow;
            gload16(Ab + (size_t)row * K + k0 + scol, &As[ch * 512]);
            gload16(Bb + (size_t)row * K + k0 + scol, &Bs[ch * 512]);
        }
        // explicit drain of global_load_lds before the barrier (replay-race fix)
        asm volatile("s_waitcnt vmcnt(0)" ::: "memory");
        __syncthreads();
#pragma unroll
        for (int kk = 0; kk < 4; kk++) {
            const int s0 = 2 * kk + hi;                 // 16B-slot index 0..7
            s16x8 af[2], bfv[2];
#pragma unroll
            for (int ni = 0; ni < 2; ni++)
                af[ni] = *(const s16x8*)&Bs[ra[ni] * BK + ((s0 ^ rax[ni]) * 8)];
#pragma unroll
            for (int mi = 0; mi < 2; mi++)
                bfv[mi] = *(const s16x8*)&As[rb[mi] * BK + ((s0 ^ rbx[mi]) * 8)];
#pragma unroll
            for (int ni = 0; ni < 2; ni++)
#pragma unroll
                for (int mi = 0; mi < 2; mi++)
                    acc[ni][mi] = __builtin_amdgcn_mfma_f32_32x32x16_bf16(
                        af[ni], bfv[mi], acc[ni][mi], 0, 0, 0);
        }
        __syncthreads();
    }

    // epilogue: D[row=feature][col=token]; reg 4*rq+r2 -> feature (8*rq+4*hi+r2)
    const int tokbase = bm * 128 + 64 * wc + l31;
    const int featbase = bn * 128 + 64 * wr + 4 * hi;
#pragma unroll
    for (int ni = 0; ni < 2; ni++) {
#pragma unroll
        for (int mi = 0; mi < 2; mi++) {
            const int tok = tokbase + 32 * mi;
#pragma unroll
            for (int rq = 0; rq < 4; rq++) {
                const int f0 = featbase + 32 * ni + 8 * rq;
                float v0 = acc[ni][mi][4 * rq + 0];
                float v1 = acc[ni][mi][4 * rq + 1];
                float v2 = acc[ni][mi][4 * rq + 2];
                float v3 = acc[ni][mi][4 * rq + 3];
                if constexpr (EPI == 0) {
                    const int which = f0 / DIM;
                    const int rem = f0 - which * DIM;
                    const int head = rem >> 5, dh = rem & 31;
                    if (which == 0) {
                        v0 *= 0.25503527f; v1 *= 0.25503527f; // (1/sqrt(32))*log2(e)
                        v2 *= 0.25503527f; v3 *= 0.25503527f;
                    }
                    const int wn = tok / WP, p = tok - wn * WP;
                    s16x4 o; o[0] = f2b(v0); o[1] = f2b(v1); o[2] = f2b(v2); o[3] = f2b(v3);
                    *(s16x4*)(out + (size_t)which * TOKDIM +
                              ((size_t)(wn * HEADS + head) * WP + p) * DH + dh) = o;
                } else if constexpr (EPI == 1) {
                    const float4 bv = *(const float4*)(bias + f0);
                    s16x4 o;
                    o[0] = f2b(v0 + bv.x); o[1] = f2b(v1 + bv.y);
                    o[2] = f2b(v2 + bv.z); o[3] = f2b(v3 + bv.w);
                    *(s16x4*)(out + (size_t)tok * N + f0) = o;
                } else {
                    const float4 bv = *(const float4*)(bias + f0);
                    float g0 = v0 + bv.x, g1 = v1 + bv.y, g2 = v2 + bv.z, g3 = v3 + bv.w;
                    g0 = 0.5f * g0 * (1.0f + erff(g0 * 0.70710678118654752f));
                    g1 = 0.5f * g1 * (1.0f + erff(g1 * 0.70710678118654752f));
                    g2 = 0.5f * g2 * (1.0f + erff(g2 * 0.70710678118654752f));
                    g3 = 0.5f * g3 * (1.0f + erff(g3 * 0.70710678118654752f));
                    s16x4 o; o[0] = f2b(g0); o[1] = f2b(g1); o[2] = f2b(g2); o[3] = f2b(g3);
                    *(s16x4*)(out + (size_t)tok * N + f0) = o;
                }
            }
        }
    }
}

// ---------------- fused window attention (round-10 proven) ----------------
// block = one (window, head); 3 waves; wave s owns strips {3s,3s+1,3s+2}.
// Q and K fragments direct from global (coalesced, L1/L2-hit); only V^T + P in LDS
// (26.4KB -> 6 blocks/CU for latency hiding). Strides 164 (conflict-free walk).
// Softmax in exp2 domain, no max-subtract, normalize O after PV.
__global__ __launch_bounds__(192)
void k_attn(const bf16* __restrict__ q, const bf16* __restrict__ kmat,
            const bf16* __restrict__ v, const bf16* __restrict__ tab,
            bf16* __restrict__ out) {
    __shared__ bf16 VTs[DH * 164];      // [32][164], cols 144..163 zero
    __shared__ bf16 Ps[3][16 * 164];    // per-wave [16][164], cols 144..159 zero
    __shared__ unsigned char regn[WP];

    const int bid = blockIdx.x;
    const int wn = bid / HEADS, head = bid - wn * HEADS;
    const int mz = wn / (MH * MW);
    const int rem = wn - mz * (MH * MW);
    const int mh = rem / MW, mw = rem - (rem / MW) * MW;
    const int tile = (mz * MH + mh) * HEADS + head;   // wt*12 + head

    const int tid = threadIdx.x;
    const int lane = tid & 63;
    const int s = tid >> 6;              // wave 0..2
    const int lg = lane >> 4, lc = lane & 15;

    const size_t base = (size_t)(wn * HEADS + head) * (WP * DH);
    // stage V transposed [32][164]
    {
        short* vt = (short*)VTs;
#pragma unroll
        for (int e2 = 0; e2 < 3; e2++) {
            int idx = tid + 192 * e2;    // 0..575
            s16x8 vv = *(const s16x8*)(v + base + idx * 8);
            int p = idx >> 2;
            int d0 = (idx & 3) * 8;
#pragma unroll
            for (int e = 0; e < 8; e++) vt[(d0 + e) * 164 + p] = vv[e];
        }
        // zero VT cols 144..163 (32 rows x 20 cols, 160 s16x4 stores)
        if (tid < 160) {
            int d = tid / 5, gq = tid - d * 5;
            *(s16x4*)(vt + d * 164 + 144 + gq * 4) = (s16x4){0, 0, 0, 0};
        }
        // zero this wave's Ps pad cols 144..159 (16 rows x 16 cols)
        { short* pz = (short*)&Ps[s][0];
          *(s16x4*)(pz + (lane >> 2) * 164 + 144 + (lane & 3) * 4) = (s16x4){0, 0, 0, 0}; }
        if (tid < WP) {
            int lz = tid / 72, rp = tid - lz * 72;
            int lh = rp / 12, lw = rp - lh * 12;
            int zr = (mz == 3) ? (lz + 1) : 0;
            int hr = (mh == 15) ? (lh < 3 ? 1 : 2) : 0;
            int wbit = (lw < 6) ? 1 : 2;
            regn[tid] = (unsigned char)((zr * 3 + hr) * 4 + wbit);
        }
    }
    __syncthreads();

    const f32x4 zf = {0.f, 0.f, 0.f, 0.f};
    const bf16* tb = tab + (size_t)tile * (WP * WP);
    const bf16* kb = kmat + base;
    bf16* ob = out + (size_t)wn * (WP * DIM) + head * DH;
    short* ps = (short*)&Ps[s][0];
    const bf16* psb = &Ps[s][0];

    for (int t = 0; t < 3; t++) {
        const int strip = 3 * s + t;
        const int ib = 16 * strip + 4 * lg;
        // Q fragment direct from global
        s16x8 aq = *(const s16x8*)(q + base + (size_t)(16 * strip + lc) * DH + 8 * lg);
        f32x4 sacc[9];
        // QK^T; K fragments direct from global (1KB coalesced per jt, L1/L2-hit)
#pragma unroll
        for (int jt = 0; jt < 9; jt++) {
            s16x8 bk = *(const s16x8*)(kb + (size_t)(16 * jt + lc) * DH + 8 * lg);
            sacc[jt] = __builtin_amdgcn_mfma_f32_16x16x32_bf16(aq, bk, zf, 0, 0, 0);
        }
        // + expanded bias (includes z/h mask), log2-scaled
#pragma unroll
        for (int jt = 0; jt < 9; jt++) {
            int j = 16 * jt + lc;
#pragma unroll
            for (int r2 = 0; r2 < 4; r2++)
                sacc[jt][r2] += __bfloat162float(tb[(ib + r2) * WP + j]);
        }
        // residual w-region mask (only boundary-mw windows)
        if (mw == 14) {
            int ri[4];
#pragma unroll
            for (int r2 = 0; r2 < 4; r2++) ri[r2] = regn[ib + r2];
#pragma unroll
            for (int jt = 0; jt < 9; jt++) {
                int rj = regn[16 * jt + lc];
#pragma unroll
                for (int r2 = 0; r2 < 4; r2++) {
                    bool m = ((ri[r2] >> 2) == (rj >> 2)) && ((ri[r2] & 3) != (rj & 3));
                    if (m) sacc[jt][r2] -= 144.2695f;
                }
            }
        }
        // exp2 (no max-subtract) + row sums
        float inv[4];
#pragma unroll
        for (int r2 = 0; r2 < 4; r2++) {
            float sum = 0.f;
#pragma unroll
            for (int jt = 0; jt < 9; jt++) {
                float pe = exp2f(sacc[jt][r2]);
                sacc[jt][r2] = pe;
                sum += pe;
            }
#pragma unroll
            for (int o = 1; o < 16; o <<= 1) sum += __shfl_xor(sum, o);
            inv[r2] = 1.0f / sum;
        }
        // store unnormalized P row-major [16][164] (wave-private; no barrier needed)
#pragma unroll
        for (int jt = 0; jt < 9; jt++)
#pragma unroll
            for (int r2 = 0; r2 < 4; r2++)
                ps[(4 * lg + r2) * 164 + 16 * jt + lc] = f2b(sacc[jt][r2]);
        // PV : O[16 x 32] (b128 fragment reads; compiler inserts lgkmcnt for RAW)
        f32x4 oacc[2] = {zf, zf};
#pragma unroll
        for (int c = 0; c < 5; c++) {
            s16x8 ap = *(const s16x8*)(psb + lc * 164 + 32 * c + 8 * lg);
#pragma unroll
            for (int nt = 0; nt < 2; nt++) {
                s16x8 bv = *(const s16x8*)(VTs + (16 * nt + lc) * 164 + 32 * c + 8 * lg);
                oacc[nt] = __builtin_amdgcn_mfma_f32_16x16x32_bf16(ap, bv, oacc[nt], 0, 0, 0);
            }
        }
#pragma unroll
        for (int nt = 0; nt < 2; nt++)
#pragma unroll
            for (int r2 = 0; r2 < 4; r2++)
                ob[(size_t)(ib + r2) * DIM + 16 * nt + lc] =
                    __float2bfloat16(oacc[nt][r2] * inv[r2]);
    }
}

// ---------------- LayerNorm kernels (wave-per-row, no LDS/barrier) ----------------

__global__ __launch_bounds__(256)
void k_ln1(const bf16* __restrict__ y, const float* __restrict__ x,
           const float* __restrict__ w, const float* __restrict__ b,
           bf16* __restrict__ x1b, int r0) {
    const int row = blockIdx.x * 4 + (threadIdx.x >> 6);
    const int l = threadIdx.x & 63;
    const int t = row_to_token(r0 + row);
    const short* yr = (const short*)y + (size_t)row * DIM;
    float v[6];
#pragma unroll
    for (int e = 0; e < 3; e++) {
        int c = 128 * e + 2 * l;
        unsigned int u = *(const unsigned int*)(yr + c);
        unsigned int lo = (u & 0xffffu) << 16, hiu = u & 0xffff0000u;
        v[2 * e]     = *reinterpret_cast<float*>(&lo);
        v[2 * e + 1] = *reinterpret_cast<float*>(&hiu);
    }
    float sum = 0.f, s2 = 0.f;
#pragma unroll
    for (int e = 0; e < 6; e++) { sum += v[e]; s2 += v[e] * v[e]; }
#pragma unroll
    for (int o = 1; o < 64; o <<= 1) { sum += __shfl_xor(sum, o); s2 += __shfl_xor(s2, o); }
    float mean = sum * (1.f / 384.f);
    float var = fmaxf(s2 * (1.f / 384.f) - mean * mean, 0.f);
    float rs = rsqrtf(var + 1e-5f);
#pragma unroll
    for (int e = 0; e < 3; e++) {
        int c = 128 * e + 2 * l;
        const float2 wv2 = *(const float2*)(w + c);
        const float2 bv2 = *(const float2*)(b + c);
        const float2 xx = *(const float2*)(x + (size_t)t * DIM + c);
        float o0 = (v[2 * e] - mean) * rs * wv2.x + bv2.x + xx.x;
        float o1 = (v[2 * e + 1] - mean) * rs * wv2.y + bv2.y + xx.y;
        short2 st; st.x = f2b(o0); st.y = f2b(o1);
        *(short2*)((short*)x1b + (size_t)t * DIM + c) = st;
    }
}

__global__ __launch_bounds__(256)
void k_ln2(const bf16* __restrict__ h, const bf16* __restrict__ x1b,
           const float* __restrict__ w, const float* __restrict__ b,
           float* __restrict__ out) {
    const int row = blockIdx.x * 4 + (threadIdx.x >> 6);
    const int l = threadIdx.x & 63;
    const short* hr = (const short*)h + (size_t)row * DIM;
    float v[6];
#pragma unroll
    for (int e = 0; e < 3; e++) {
        int c = 128 * e + 2 * l;
        unsigned int u = *(const unsigned int*)(hr + c);
        unsigned int lo = (u & 0xffffu) << 16, hiu = u & 0xffff0000u;
        v[2 * e]     = *reinterpret_cast<float*>(&lo);
        v[2 * e + 1] = *reinterpret_cast<float*>(&hiu);
    }
    float sum = 0.f, s2 = 0.f;
#pragma unroll
    for (int e = 0; e < 6; e++) { sum += v[e]; s2 += v[e] * v[e]; }
#pragma unroll
    for (int o = 1; o < 64; o <<= 1) { sum += __shfl_xor(sum, o); s2 += __shfl_xor(s2, o); }
    float mean = sum * (1.f / 384.f);
    float var = fmaxf(s2 * (1.f / 384.f) - mean * mean, 0.f);
    float rs = rsqrtf(var + 1e-5f);
    const short* xr = (const short*)x1b + (size_t)row * DIM;
#pragma unroll
    for (int e = 0; e < 3; e++) {
        int c = 128 * e + 2 * l;
        const float2 wv2 = *(const float2*)(w + c);
        const float2 bv2 = *(const float2*)(b + c);
        unsigned int u = *(const unsigned int*)(xr + c);
        unsigned int lo = (u & 0xffffu) << 16, hiu = u & 0xffff0000u;
        float2 o2;
        o2.x = (v[2 * e] - mean) * rs * wv2.x + bv2.x + *reinterpret_cast<float*>(&lo);
        o2.y = (v[2 * e + 1] - mean) * rs * wv2.y + bv2.y + *reinterpret_cast<float*>(&hiu);
        *(float2*)(out + (size_t)row * DIM + c) = o2;
    }
}

// ---------------- launcher ----------------
// Workspace map (bytes):
//  0         wqkvT(884736) wprojT(294912) w1T(1179648) w2T(1179648)
//  3538944   btr f32 (10174464)
//  13713408  tab bf16 (31850496)
//  45563904  D1: qkv (318504960) -> x1b(106168320) + ytmp/h1c(141557760 @D1+106168320)
//  364068864 D2: xw -> aout -> htmp (106168320)
//  peak 470237184

extern "C" void kernel_launch(void* const* d_in, const int* in_sizes, int n_in,
                              void* d_out, int out_size, void* d_ws, size_t ws_size,
                              hipStream_t stream) {
    const float* x      = (const float*)d_in[0];
    const float* w_qkv  = (const float*)d_in[1];
    const float* w_proj = (const float*)d_in[2];
    const float* b_proj = (const float*)d_in[3];
    const float* btab   = (const float*)d_in[4];
    const float* ln1w   = (const float*)d_in[5];
    const float* ln1b   = (const float*)d_in[6];
    const float* ln2w   = (const float*)d_in[7];
    const float* ln2b   = (const float*)d_in[8];
    const float* w1     = (const float*)d_in[9];
    const float* b1     = (const float*)d_in[10];
    const float* w2     = (const float*)d_in[11];
    const float* b2     = (const float*)d_in[12];

    const size_t NEED = 470237184ULL;
    if (ws_size < NEED) {
        k_fill<<<(out_size + 255) / 256, 256, 0, stream>>>((float*)d_out, out_size, 12345.0f);
        return;
    }

    char* ws = (char*)d_ws;
    bf16* wqkvT  = (bf16*)(ws + 0);
    bf16* wprojT = (bf16*)(ws + 884736);
    bf16* w1T    = (bf16*)(ws + 1179648);
    bf16* w2T    = (bf16*)(ws + 2359296);
    float* btr   = (float*)(ws + 3538944);
    bf16* tab    = (bf16*)(ws + 13713408);

    const size_t D1 = 45563904;
    const size_t D2 = 364068864;

    bf16* qkv  = (bf16*)(ws + D1);
    bf16* x1b  = (bf16*)(ws + D1);
    bf16* ytmp = (bf16*)(ws + D1 + 106168320);
    bf16* h1c  = (bf16*)(ws + D1 + 106168320);
    bf16* xw   = (bf16*)(ws + D2);
    bf16* aout = (bf16*)(ws + D2);
    bf16* htmp = (bf16*)(ws + D2);

    // prep
    k_wcast<<<(442368 + 255) / 256, 256, 0, stream>>>(w_qkv, wqkvT, 384, 1152);
    k_wcast<<<(147456 + 255) / 256, 256, 0, stream>>>(w_proj, wprojT, 384, 384);
    k_wcast<<<(589824 + 255) / 256, 256, 0, stream>>>(w1, w1T, 384, 1536);
    k_wcast<<<(589824 + 255) / 256, 256, 0, stream>>>(w2, w2T, 1536, 384);
    k_btr<<<(2543616 + 255) / 256, 256, 0, stream>>>(btab, btr);
    k_mktab<<<(768 * WP * WP + 255) / 256, 256, 0, stream>>>(btr, tab);
    k_gather_x<<<(TOK * 96 + 255) / 256, 256, 0, stream>>>(x, xw);

    // qkv = xw @ w_qkv (scatter epilogue)
    k_gemm<0><<<dim3((TOK / 128) * 9), 256, 0, stream>>>(xw, wqkvT, nullptr, qkv, TOK, 1152, 384);

    // attention (192 threads, 3 waves, 6 blocks/CU)
    k_attn<<<dim3(WN * HEADS), 192, 0, stream>>>(qkv, qkv + TOKDIM, qkv + 2 * TOKDIM, tab, aout);

    // proj + LN1 + residual (chunked; qkv region becomes x1b)
    for (int c = 0; c < NC; c++) {
        k_gemm<1><<<dim3((CM / 128) * 3), 256, 0, stream>>>(
            aout + (size_t)c * CM * DIM, wprojT, b_proj, ytmp, CM, 384, 384);
        k_ln1<<<dim3(CM / 4), 256, 0, stream>>>(ytmp, x, ln1w, ln1b, x1b, c * CM);
    }

    // MLP (chunked)
    for (int c = 0; c < NC; c++) {
        k_gemm<2><<<dim3((CM / 128) * 12), 256, 0, stream>>>(
            x1b + (size_t)c * CM * DIM, w1T, b1, h1c, CM, 1536, 384);
        k_gemm<1><<<dim3((CM / 128) * 3), 256, 0, stream>>>(
            h1c, w2T, b2, htmp + (size_t)c * CM * DIM, CM, 384, 1536);
    }

    // final LN + residual -> d_out (fp32)
    k_ln2<<<dim3(TOK / 4), 256, 0, stream>>>(htmp, x1b, ln2w, ln2b, (float*)d_out);
}